// Round 1
// baseline (320.047 us; speedup 1.0000x reference)
//
#include <hip/hip_runtime.h>
#include <math.h>

#define NBINS 15

// gbins layout in d_ws: [0..14]=counts, [15..29]=sum_conf, [30..44]=sum_acc
__global__ __launch_bounds__(256) void ece_main(const float* __restrict__ logits,
                                                const int* __restrict__ labels,
                                                const int* __restrict__ t_opt,
                                                float* __restrict__ gbins,
                                                int N, int C) {
    __shared__ float s_cnt[NBINS], s_conf[NBINS], s_acc[NBINS];
    const int tid = threadIdx.x;
    if (tid < NBINS) { s_cnt[tid] = 0.f; s_conf[tid] = 0.f; s_acc[tid] = 0.f; }
    __syncthreads();

    const int lane = tid & 63;
    const int wid  = tid >> 6;
    const int wavesPerBlock = blockDim.x >> 6;
    const long long waveGlobal = (long long)blockIdx.x * wavesPerBlock + wid;
    const long long nWaves = (long long)gridDim.x * wavesPerBlock;

    const int t = t_opt[0];
    const float inv_t = (t != 0) ? (1.0f / (float)t) : 1.0f;

    for (long long row = waveGlobal; row < N; row += nWaves) {
        const float* rp = logits + row * (long long)C;

        float v0 = -INFINITY, v1 = -INFINITY;
        if (lane < C)      v0 = rp[lane] * inv_t;
        if (lane + 64 < C) v1 = rp[lane + 64] * inv_t;

        // per-lane max + argmax (prefer lower index on tie)
        float m;  int mi;
        if (v1 > v0) { m = v1; mi = lane + 64; } else { m = v0; mi = lane; }

        // wave butterfly reduce: max value, first (lowest) index on tie
        #pragma unroll
        for (int off = 1; off < 64; off <<= 1) {
            float om  = __shfl_xor(m, off);
            int   omi = __shfl_xor(mi, off);
            if (om > m || (om == m && omi < mi)) { m = om; mi = omi; }
        }

        // sum of exp(x - m)
        float e = 0.f;
        if (lane < C)      e += __expf(v0 - m);
        if (lane + 64 < C) e += __expf(v1 - m);
        #pragma unroll
        for (int off = 1; off < 64; off <<= 1) e += __shfl_xor(e, off);

        if (lane == 0) {
            const float conf = 1.0f / e;               // max(softmax) = exp(0)/sum
            const float acc  = (mi == labels[row]) ? 1.0f : 0.0f;

            // searchsorted(linspace(0,1,16), conf, side='left') - 1, clipped
            int j = 0;
            #pragma unroll
            for (int i = 0; i <= NBINS; ++i) {
                const float b = (float)i * (1.0f / 15.0f);
                j += (b < conf) ? 1 : 0;
            }
            int bin = j - 1;
            bin = bin < 0 ? 0 : (bin > NBINS - 1 ? NBINS - 1 : bin);

            atomicAdd(&s_cnt[bin],  1.0f);
            atomicAdd(&s_conf[bin], conf);
            atomicAdd(&s_acc[bin],  acc);
        }
    }
    __syncthreads();

    if (tid < NBINS) {
        atomicAdd(&gbins[tid],             s_cnt[tid]);
        atomicAdd(&gbins[NBINS + tid],     s_conf[tid]);
        atomicAdd(&gbins[2 * NBINS + tid], s_acc[tid]);
    }
}

__global__ void ece_final(const float* __restrict__ gbins,
                          float* __restrict__ out, int N) {
    if (threadIdx.x == 0 && blockIdx.x == 0) {
        float ece = 0.f;
        for (int b = 0; b < NBINS; ++b) {
            const float c = gbins[b];
            if (c > 0.f) {
                const float avg_conf = gbins[NBINS + b] / c;
                const float avg_acc  = gbins[2 * NBINS + b] / c;
                ece += fabsf(avg_conf - avg_acc) * (c / (float)N);
            }
        }
        out[0] = ece;
    }
}

extern "C" void kernel_launch(void* const* d_in, const int* in_sizes, int n_in,
                              void* d_out, int out_size, void* d_ws, size_t ws_size,
                              hipStream_t stream) {
    const float* logits = (const float*)d_in[0];
    const int*   labels = (const int*)d_in[1];
    const int*   t_opt  = (const int*)d_in[2];
    float* out   = (float*)d_out;
    float* gbins = (float*)d_ws;

    const int N = in_sizes[1];          // 1,000,000
    const int C = in_sizes[0] / N;      // 100

    hipMemsetAsync(gbins, 0, 3 * NBINS * sizeof(float), stream);

    const int blocks = 2048;            // 2048 blocks x 4 waves = 8192 waves, grid-stride
    ece_main<<<blocks, 256, 0, stream>>>(logits, labels, t_opt, gbins, N, C);
    ece_final<<<1, 64, 0, stream>>>(gbins, out, N);
}

// Round 2
// 138.611 us; speedup vs baseline: 2.3090x; 2.3090x over previous
//
#include <hip/hip_runtime.h>
#include <math.h>

#define NBINS 15
#define TILE_ROWS 128
#define ROW_PAD 101          // 100 floats + 1 pad -> bank stride 5, conflict-free
#define BLOCK 256

// gbins layout in d_ws: [0..14]=counts, [15..29]=sum_conf, [30..44]=sum_acc
__global__ __launch_bounds__(BLOCK, 3) void ece_main(const float* __restrict__ logits,
                                                     const int* __restrict__ labels,
                                                     const int* __restrict__ t_opt,
                                                     float* __restrict__ gbins,
                                                     int N) {
    __shared__ float s_tile[TILE_ROWS * ROW_PAD];   // 51.7 KB
    __shared__ float s_cnt[NBINS], s_conf[NBINS], s_acc[NBINS];

    const int tid = threadIdx.x;
    if (tid < NBINS) { s_cnt[tid] = 0.f; s_conf[tid] = 0.f; s_acc[tid] = 0.f; }
    __syncthreads();

    const int t = t_opt[0];
    const float scale = (t != 0) ? (1.0f / (float)t) : 1.0f;

    const int r = tid >> 1;      // row within tile (0..127)
    const int h = tid & 1;       // half of the row (0: cols 0..49, 1: cols 50..99)
    const int nTiles = (N + TILE_ROWS - 1) / TILE_ROWS;

    for (int tile = blockIdx.x; tile < nTiles; tile += gridDim.x) {
        const int base = tile * TILE_ROWS;
        const int rowsHere = min(TILE_ROWS, N - base);
        const int nF4 = rowsHere * 25;                       // 25 float4 per row (C=100)
        const float4* __restrict__ src =
            (const float4*)(logits + (long long)base * 100);

        // ---- stage tile: contiguous global range, coalesced float4 loads ----
        #pragma unroll
        for (int i = 0; i < 13; ++i) {
            const int k = tid + i * BLOCK;
            if (k < nF4) {
                const float4 v = src[k];
                const int rr = (k * 5243) >> 17;             // k / 25  (exact for k < 43690)
                const int cc = k - rr * 25;                  // k % 25
                float* dst = &s_tile[rr * ROW_PAD + cc * 4];
                dst[0] = v.x; dst[1] = v.y; dst[2] = v.z; dst[3] = v.w;
            }
        }
        __syncthreads();

        // ---- compute: 2 threads per row, 50 elems each ----
        const int row = base + r;
        if (row < N) {                                       // uniform within each pair
            const float* __restrict__ rp = &s_tile[r * ROW_PAD + h * 50];

            // pass 1: max + argmax (first index wins ties)
            float m = -INFINITY; int mi = 0;
            #pragma unroll
            for (int j = 0; j < 50; ++j) {
                const float v = rp[j] * scale;
                if (v > m) { m = v; mi = h * 50 + j; }
            }
            const float om  = __shfl_xor(m, 1);
            const int   omi = __shfl_xor(mi, 1);
            if (om > m || (om == m && omi < mi)) { m = om; mi = omi; }

            // pass 2: sum of exp(x - m)
            float e = 0.f;
            #pragma unroll
            for (int j = 0; j < 50; ++j) e += __expf(rp[j] * scale - m);
            e += __shfl_xor(e, 1);

            if (h == 0) {
                const float conf = 1.0f / e;                 // max softmax prob
                const float acc  = (mi == labels[row]) ? 1.0f : 0.0f;

                // searchsorted(linspace(0,1,16), conf, 'left') - 1, clipped
                int jc = 0;
                #pragma unroll
                for (int i = 0; i <= NBINS; ++i) {
                    const float b = (float)i * (1.0f / 15.0f);
                    jc += (b < conf) ? 1 : 0;
                }
                int bin = jc - 1;
                bin = bin < 0 ? 0 : (bin > NBINS - 1 ? NBINS - 1 : bin);

                atomicAdd(&s_cnt[bin],  1.0f);
                atomicAdd(&s_conf[bin], conf);
                atomicAdd(&s_acc[bin],  acc);
            }
        }
        __syncthreads();   // protect s_tile before next stage; also orders hist atomics
    }

    if (tid < NBINS) {
        atomicAdd(&gbins[tid],             s_cnt[tid]);
        atomicAdd(&gbins[NBINS + tid],     s_conf[tid]);
        atomicAdd(&gbins[2 * NBINS + tid], s_acc[tid]);
    }
}

__global__ void ece_final(const float* __restrict__ gbins,
                          float* __restrict__ out, int N) {
    if (threadIdx.x == 0 && blockIdx.x == 0) {
        float ece = 0.f;
        for (int b = 0; b < NBINS; ++b) {
            const float c = gbins[b];
            if (c > 0.f) {
                const float avg_conf = gbins[NBINS + b] / c;
                const float avg_acc  = gbins[2 * NBINS + b] / c;
                ece += fabsf(avg_conf - avg_acc) * (c / (float)N);
            }
        }
        out[0] = ece;
    }
}

extern "C" void kernel_launch(void* const* d_in, const int* in_sizes, int n_in,
                              void* d_out, int out_size, void* d_ws, size_t ws_size,
                              hipStream_t stream) {
    const float* logits = (const float*)d_in[0];
    const int*   labels = (const int*)d_in[1];
    const int*   t_opt  = (const int*)d_in[2];
    float* out   = (float*)d_out;
    float* gbins = (float*)d_ws;

    const int N = in_sizes[1];               // 1,000,000 rows (C fixed at 100)

    hipMemsetAsync(gbins, 0, 3 * NBINS * sizeof(float), stream);

    const int nTiles = (N + TILE_ROWS - 1) / TILE_ROWS;
    const int blocks = nTiles < 768 ? nTiles : 768;   // 3 blocks/CU x 256 CU
    ece_main<<<blocks, BLOCK, 0, stream>>>(logits, labels, t_opt, gbins, N);
    ece_final<<<1, 64, 0, stream>>>(gbins, out, N);
}

// Round 3
// 96.115 us; speedup vs baseline: 3.3298x; 1.4421x over previous
//
#include <hip/hip_runtime.h>
#include <math.h>

#define NBINS 15
#define TILE_ROWS 128
#define NC 100
#define BLOCK 256
#define TILE_BYTES (TILE_ROWS * NC * 4)   // 51200 B = exact contiguous copy of global
#define CHUNKS (TILE_BYTES / 1024)        // 50 x 1KB wave-chunks

typedef __attribute__((address_space(3))) unsigned int lds_u32;
typedef __attribute__((address_space(1))) const unsigned int glob_u32;

// gbins layout in d_ws: [0..14]=counts, [15..29]=sum_conf, [30..44]=sum_acc
__global__ __launch_bounds__(BLOCK, 3) void ece_main(const float* __restrict__ logits,
                                                     const int* __restrict__ labels,
                                                     const int* __restrict__ t_opt,
                                                     float* __restrict__ gbins,
                                                     int N) {
    __shared__ float s_tile[TILE_ROWS * NC];   // 51.2 KB, linear (global_load_lds dest)
    __shared__ float s_cnt[NBINS], s_conf[NBINS], s_acc[NBINS];

    const int tid  = threadIdx.x;
    if (tid < NBINS) { s_cnt[tid] = 0.f; s_conf[tid] = 0.f; s_acc[tid] = 0.f; }

    const int lane = tid & 63;
    const int wv   = tid >> 6;                 // wave id 0..3
    const int r    = tid >> 1;                 // row within tile 0..127
    const int h    = tid & 1;                  // half: 0 -> f4 chunks 0..12, 1 -> 13..24

    const int t = t_opt[0];
    const float scale = (t != 0) ? (1.0f / (float)t) : 1.0f;
    const int nTiles = (N + TILE_ROWS - 1) / TILE_ROWS;

    for (int tile = blockIdx.x; tile < nTiles; tile += gridDim.x) {
        const long long base = (long long)tile * TILE_ROWS;
        const int rowsHere  = min(TILE_ROWS, (int)(N - base));
        const int bytesHere = rowsHere * (NC * 4);
        const char* gsrc = (const char*)(logits + base * NC);

        __syncthreads();   // protect s_tile from previous iteration's readers

        // ---- stage: async global->LDS, 16B/lane, 1KB per wave-chunk ----
        #pragma unroll
        for (int i = 0; i < 13; ++i) {
            const int c = wv + i * 4;                  // chunk id, wave-uniform
            if (c < CHUNKS) {
                const int off = c * 1024 + lane * 16;  // per-lane global offset
                if (off < bytesHere) {
                    __builtin_amdgcn_global_load_lds(
                        (glob_u32*)(gsrc + off),
                        (lds_u32*)((char*)s_tile + c * 1024),  // wave-uniform base
                        16, 0, 0);
                }
            }
        }
        __syncthreads();   // drains vmcnt before any reads

        // ---- compute: 2 threads/row, 13 (h=0) or 12 (h=1) float4 each ----
        if (base + r < N) {
            const float4* rowp = (const float4*)&s_tile[r * NC];
            const int n4 = 13 - h;

            float4 v[13];
            #pragma unroll
            for (int j = 0; j < 13; ++j)
                if (j < n4) v[j] = rowp[h * 13 + j];   // ds_read_b128, static idx

            // pass 1: max + argmax (first index wins ties)
            float m = -INFINITY; int mi = 0;
            #pragma unroll
            for (int j = 0; j < 13; ++j) if (j < n4) {
                const int cb = (h * 13 + j) * 4;
                float4 w = v[j];
                w.x *= scale; w.y *= scale; w.z *= scale; w.w *= scale;
                v[j] = w;
                if (w.x > m) { m = w.x; mi = cb;     }
                if (w.y > m) { m = w.y; mi = cb + 1; }
                if (w.z > m) { m = w.z; mi = cb + 2; }
                if (w.w > m) { m = w.w; mi = cb + 3; }
            }
            const float om  = __shfl_xor(m, 1);
            const int   omi = __shfl_xor(mi, 1);
            if (om > m || (om == m && omi < mi)) { m = om; mi = omi; }

            // pass 2: sum exp(x - m) from registers
            float e = 0.f;
            #pragma unroll
            for (int j = 0; j < 13; ++j) if (j < n4) {
                const float4 w = v[j];
                e += __expf(w.x - m) + __expf(w.y - m)
                   + __expf(w.z - m) + __expf(w.w - m);
            }
            e += __shfl_xor(e, 1);

            if (h == 0) {
                const float conf = 1.0f / e;
                const float acc  = (mi == labels[base + r]) ? 1.0f : 0.0f;

                // searchsorted(linspace(0,1,16), conf, 'left') - 1, clipped
                int jc = 0;
                #pragma unroll
                for (int i = 0; i <= NBINS; ++i) {
                    const float b = (float)i * (1.0f / 15.0f);
                    jc += (b < conf) ? 1 : 0;
                }
                int bin = jc - 1;
                bin = bin < 0 ? 0 : (bin > NBINS - 1 ? NBINS - 1 : bin);

                atomicAdd(&s_cnt[bin],  1.0f);
                atomicAdd(&s_conf[bin], conf);
                atomicAdd(&s_acc[bin],  acc);
            }
        }
    }

    __syncthreads();   // all histogram atomics done before flush
    if (tid < NBINS) {
        atomicAdd(&gbins[tid],             s_cnt[tid]);
        atomicAdd(&gbins[NBINS + tid],     s_conf[tid]);
        atomicAdd(&gbins[2 * NBINS + tid], s_acc[tid]);
    }
}

__global__ void ece_final(const float* __restrict__ gbins,
                          float* __restrict__ out, int N) {
    if (threadIdx.x == 0 && blockIdx.x == 0) {
        float ece = 0.f;
        for (int b = 0; b < NBINS; ++b) {
            const float c = gbins[b];
            if (c > 0.f) {
                const float avg_conf = gbins[NBINS + b] / c;
                const float avg_acc  = gbins[2 * NBINS + b] / c;
                ece += fabsf(avg_conf - avg_acc) * (c / (float)N);
            }
        }
        out[0] = ece;
    }
}

extern "C" void kernel_launch(void* const* d_in, const int* in_sizes, int n_in,
                              void* d_out, int out_size, void* d_ws, size_t ws_size,
                              hipStream_t stream) {
    const float* logits = (const float*)d_in[0];
    const int*   labels = (const int*)d_in[1];
    const int*   t_opt  = (const int*)d_in[2];
    float* out   = (float*)d_out;
    float* gbins = (float*)d_ws;

    const int N = in_sizes[1];               // 1,000,000 rows (C fixed at 100)

    hipMemsetAsync(gbins, 0, 3 * NBINS * sizeof(float), stream);

    const int nTiles = (N + TILE_ROWS - 1) / TILE_ROWS;
    const int blocks = nTiles < 768 ? nTiles : 768;   // 3 blocks/CU x 256 CU
    ece_main<<<blocks, BLOCK, 0, stream>>>(logits, labels, t_opt, gbins, N);
    ece_final<<<1, 64, 0, stream>>>(gbins, out, N);
}